// Round 2
// baseline (1608.706 us; speedup 1.0000x reference)
//
#include <hip/hip_runtime.h>
#include <math.h>

#define NN 50000
#define EE 800000
#define NEG 0.2f

__device__ __forceinline__ float lrelu(float x){ return x > 0.f ? x : NEG*x; }

// ---------------------------------------------------------------------------
// Fusion: h0[n][c] = elu( sum_r fw[r] * fc[r,n,c]*ft[r,n,c]*fr[r,n,c] + fb[c] )
// fc = h_common @ Wc[r]  (K=129), ft/fr with K=513.
// Block: 256 threads = 64 c-lanes x 4 groups; tile = 32 nodes (8 per group).
// LDS stages feature chunks transposed sf[ii][node] (pad 36) so inner reads
// are wave-broadcast float4s.
// ---------------------------------------------------------------------------
__device__ __forceinline__ void gemm_pass(
    const float* __restrict__ F, const float* __restrict__ W, int K,
    int nbase, int c, int g, int tid, float (&acc)[4][8], float (*sf)[36])
{
#pragma unroll
    for (int r = 0; r < 4; ++r)
#pragma unroll
        for (int q = 0; q < 8; ++q) acc[r][q] = 0.f;

    for (int ib = 0; ib < K; ib += 64) {
        int cw = min(64, K - ib);
        __syncthreads();
        for (int idx = tid; idx < 32 * cw; idx += 256) {
            int nl = idx / cw, ii = idx - nl * cw;
            int n = nbase + nl;
            sf[ii][nl] = (n < NN) ? F[(size_t)n * K + ib + ii] : 0.f;
        }
        __syncthreads();
        const size_t rstride = (size_t)K * 64;
        for (int ii = 0; ii < cw; ++ii) {
            const float* wp = W + (size_t)(ib + ii) * 64 + c;
            float w0 = wp[0];
            float w1 = wp[rstride];
            float w2 = wp[2 * rstride];
            float w3 = wp[3 * rstride];
            float4 f0 = *(const float4*)&sf[ii][g * 8];
            float4 f1 = *(const float4*)&sf[ii][g * 8 + 4];
            float fv[8] = {f0.x, f0.y, f0.z, f0.w, f1.x, f1.y, f1.z, f1.w};
#pragma unroll
            for (int q = 0; q < 8; ++q) {
                acc[0][q] += w0 * fv[q];
                acc[1][q] += w1 * fv[q];
                acc[2][q] += w2 * fv[q];
                acc[3][q] += w3 * fv[q];
            }
        }
    }
}

__global__ __launch_bounds__(256) void fusion_kernel(
    const float* __restrict__ hc, const float* __restrict__ ht, const float* __restrict__ hr,
    const float* __restrict__ Wc, const float* __restrict__ Wt, const float* __restrict__ Wr,
    const float* __restrict__ fw, const float* __restrict__ fb,
    float* __restrict__ h0)
{
    __shared__ float sf[64][36];
    const int tid = threadIdx.x;
    const int c = tid & 63, g = tid >> 6;
    const int nbase = blockIdx.x * 32;

    float accA[4][8];
    float accB[4][8];

    gemm_pass(hc, Wc, 129, nbase, c, g, tid, accA, sf);
    gemm_pass(ht, Wt, 513, nbase, c, g, tid, accB, sf);
#pragma unroll
    for (int r = 0; r < 4; ++r)
#pragma unroll
        for (int q = 0; q < 8; ++q) accA[r][q] *= accB[r][q];
    gemm_pass(hr, Wr, 513, nbase, c, g, tid, accB, sf);

    float fw0 = fw[0], fw1 = fw[1], fw2 = fw[2], fw3 = fw[3];
    float fbc = fb[c];
#pragma unroll
    for (int q = 0; q < 8; ++q) {
        int n = nbase + g * 8 + q;
        if (n < NN) {
            float v = fbc + fw0 * accA[0][q] * accB[0][q]
                          + fw1 * accA[1][q] * accB[1][q]
                          + fw2 * accA[2][q] * accB[2][q]
                          + fw3 * accA[3][q] * accB[3][q];
            v = v > 0.f ? v : expm1f(v);
            h0[(size_t)n * 64 + c] = v;
        }
    }
}

// ---------------------------------------------------------------------------
// feat[n][j] = sum_k hin[n][k] * W[k][j], j in [0,256). Tile 32 nodes/block.
// Thread = (4 consecutive j cols) x (8 nodes).
// ---------------------------------------------------------------------------
template <int K>
__global__ __launch_bounds__(256) void gemm_feat(
    const float* __restrict__ hin, const float* __restrict__ W,
    float* __restrict__ feat)
{
    __shared__ float sh[K][36];
    const int tid = threadIdx.x;
    const int j0 = (tid & 63) * 4;
    const int g = tid >> 6;
    const int nbase = blockIdx.x * 32;

    for (int idx = tid; idx < 32 * K; idx += 256) {
        int nl = idx / K, k = idx - nl * K;
        int n = nbase + nl;
        sh[k][nl] = (n < NN) ? hin[(size_t)n * K + k] : 0.f;
    }
    __syncthreads();

    float acc[8][4];
#pragma unroll
    for (int q = 0; q < 8; ++q)
#pragma unroll
        for (int j = 0; j < 4; ++j) acc[q][j] = 0.f;

    for (int k = 0; k < K; ++k) {
        float4 w = *(const float4*)(W + (size_t)k * 256 + j0);
        float4 fA = *(const float4*)&sh[k][g * 8];
        float4 fB = *(const float4*)&sh[k][g * 8 + 4];
        float fv[8] = {fA.x, fA.y, fA.z, fA.w, fB.x, fB.y, fB.z, fB.w};
#pragma unroll
        for (int q = 0; q < 8; ++q) {
            acc[q][0] += fv[q] * w.x;
            acc[q][1] += fv[q] * w.y;
            acc[q][2] += fv[q] * w.z;
            acc[q][3] += fv[q] * w.w;
        }
    }
#pragma unroll
    for (int q = 0; q < 8; ++q) {
        int n = nbase + g * 8 + q;
        if (n < NN) {
            float4 o = make_float4(acc[q][0], acc[q][1], acc[q][2], acc[q][3]);
            *(float4*)(feat + (size_t)n * 256 + j0) = o;
        }
    }
}

// ---------------------------------------------------------------------------
// el[n][h] = sum_d feat[n][h*64+d]*al[h][d]; er likewise. One wave per node.
// ---------------------------------------------------------------------------
__global__ __launch_bounds__(256) void elr_kernel(
    const float* __restrict__ feat, const float* __restrict__ al, const float* __restrict__ ar,
    float* __restrict__ el, float* __restrict__ er)
{
    int wid = (int)((blockIdx.x * (size_t)blockDim.x + threadIdx.x) >> 6);
    int lane = threadIdx.x & 63;
    if (wid >= NN) return;
    float elh[4], erh[4];
#pragma unroll
    for (int h = 0; h < 4; ++h) {
        float x = feat[(size_t)wid * 256 + h * 64 + lane];
        elh[h] = x * al[h * 64 + lane];
        erh[h] = x * ar[h * 64 + lane];
    }
#pragma unroll
    for (int off = 32; off; off >>= 1) {
#pragma unroll
        for (int h = 0; h < 4; ++h) {
            elh[h] += __shfl_xor(elh[h], off);
            erh[h] += __shfl_xor(erh[h], off);
        }
    }
    if (lane == 0) {
        *(float4*)(el + (size_t)wid * 4) = make_float4(elh[0], elh[1], elh[2], elh[3]);
        *(float4*)(er + (size_t)wid * 4) = make_float4(erh[0], erh[1], erh[2], erh[3]);
    }
}

// ---------------------------------------------------------------------------
// CSR build
// ---------------------------------------------------------------------------
__global__ void hist_kernel(const int* __restrict__ dst, int* __restrict__ cnt)
{
    int e = blockIdx.x * blockDim.x + threadIdx.x;
    if (e < EE) atomicAdd(&cnt[dst[e]], 1);
}

__global__ __launch_bounds__(1024) void scan_kernel(const int* __restrict__ cnt, int* __restrict__ offs)
{
    __shared__ int tmp[1024];
    const int t = threadIdx.x;
    const int C = (NN + 1023) / 1024;
    int lo = t * C, hi = min(lo + C, NN);
    int s = 0;
    for (int i = lo; i < hi; ++i) s += cnt[i];
    tmp[t] = s;
    __syncthreads();
    for (int off = 1; off < 1024; off <<= 1) {
        int v = (t >= off) ? tmp[t - off] : 0;
        __syncthreads();
        tmp[t] += v;
        __syncthreads();
    }
    int run = (t == 0) ? 0 : tmp[t - 1];
    for (int i = lo; i < hi; ++i) { offs[i] = run; run += cnt[i]; }
    if (t == 1023) offs[NN] = tmp[1023];
}

__global__ void scatter_kernel(const int* __restrict__ dst, const int* __restrict__ offs,
                               int* __restrict__ cur, int* __restrict__ esort)
{
    int e = blockIdx.x * blockDim.x + threadIdx.x;
    if (e < EE) {
        int d = dst[e];
        int p = offs[d] + atomicAdd(&cur[d], 1);
        esort[p] = e;
    }
}

// ---------------------------------------------------------------------------
// Per-dst softmax + aggregation. One wave per destination node, lane = d.
// Pass A: per-head max; Pass B: sum of exp; Pass C: weighted accumulate
// (wave-uniform edge loop, coalesced 256B feature row loads per head).
// ---------------------------------------------------------------------------
template <int RESID, int WATT>
__global__ __launch_bounds__(256) void gat_agg(
    const int* __restrict__ esort, const int* __restrict__ src, const int* __restrict__ offs,
    const float* __restrict__ feat, const float* __restrict__ el, const float* __restrict__ er,
    const float* __restrict__ resid, const float* __restrict__ bias,
    float* __restrict__ out, float* __restrict__ att)
{
    int n = (int)((blockIdx.x * (size_t)blockDim.x + threadIdx.x) >> 6);
    int lane = threadIdx.x & 63;
    if (n >= NN) return;
    int s0 = offs[n], s1 = offs[n + 1];
    float4 e4 = *(const float4*)(er + (size_t)n * 4);

    float m0 = -1e30f, m1 = -1e30f, m2 = -1e30f, m3 = -1e30f;
    for (int p = s0 + lane; p < s1; p += 64) {
        int e = esort[p]; int s = src[e];
        float4 l4 = *(const float4*)(el + (size_t)s * 4);
        m0 = fmaxf(m0, lrelu(l4.x + e4.x));
        m1 = fmaxf(m1, lrelu(l4.y + e4.y));
        m2 = fmaxf(m2, lrelu(l4.z + e4.z));
        m3 = fmaxf(m3, lrelu(l4.w + e4.w));
    }
#pragma unroll
    for (int off = 32; off; off >>= 1) {
        m0 = fmaxf(m0, __shfl_xor(m0, off));
        m1 = fmaxf(m1, __shfl_xor(m1, off));
        m2 = fmaxf(m2, __shfl_xor(m2, off));
        m3 = fmaxf(m3, __shfl_xor(m3, off));
    }

    float z0 = 0.f, z1 = 0.f, z2 = 0.f, z3 = 0.f;
    for (int p = s0 + lane; p < s1; p += 64) {
        int e = esort[p]; int s = src[e];
        float4 l4 = *(const float4*)(el + (size_t)s * 4);
        z0 += expf(lrelu(l4.x + e4.x) - m0);
        z1 += expf(lrelu(l4.y + e4.y) - m1);
        z2 += expf(lrelu(l4.z + e4.z) - m2);
        z3 += expf(lrelu(l4.w + e4.w) - m3);
    }
#pragma unroll
    for (int off = 32; off; off >>= 1) {
        z0 += __shfl_xor(z0, off);
        z1 += __shfl_xor(z1, off);
        z2 += __shfl_xor(z2, off);
        z3 += __shfl_xor(z3, off);
    }
    float i0 = z0 > 0.f ? 1.f / z0 : 0.f;
    float i1 = z1 > 0.f ? 1.f / z1 : 0.f;
    float i2 = z2 > 0.f ? 1.f / z2 : 0.f;
    float i3 = z3 > 0.f ? 1.f / z3 : 0.f;

    float a0 = 0.f, a1 = 0.f, a2 = 0.f, a3 = 0.f;
    for (int p = s0; p < s1; ++p) {
        int e = esort[p]; int s = src[e];
        float4 l4 = *(const float4*)(el + (size_t)s * 4);
        float w0 = expf(lrelu(l4.x + e4.x) - m0) * i0;
        float w1 = expf(lrelu(l4.y + e4.y) - m1) * i1;
        float w2 = expf(lrelu(l4.z + e4.z) - m2) * i2;
        float w3 = expf(lrelu(l4.w + e4.w) - m3) * i3;
        const float* fp = feat + (size_t)s * 256;
        a0 += w0 * fp[lane];
        a1 += w1 * fp[64 + lane];
        a2 += w2 * fp[128 + lane];
        a3 += w3 * fp[192 + lane];
        if (WATT && lane < 4) {
            float wl = lane == 0 ? w0 : lane == 1 ? w1 : lane == 2 ? w2 : w3;
            att[(size_t)e * 4 + lane] = wl;
        }
    }
    float o0 = a0 + bias[lane];
    float o1 = a1 + bias[64 + lane];
    float o2 = a2 + bias[128 + lane];
    float o3 = a3 + bias[192 + lane];
    if (RESID) {
        const float* rp = resid + (size_t)n * 256;
        o0 += rp[lane];
        o1 += rp[64 + lane];
        o2 += rp[128 + lane];
        o3 += rp[192 + lane];
    }
    float* op = out + (size_t)n * 256;
    op[lane] = o0;
    op[64 + lane] = o1;
    op[128 + lane] = o2;
    op[192 + lane] = o3;
}

// ---------------------------------------------------------------------------
extern "C" void kernel_launch(void* const* d_in, const int* in_sizes, int n_in,
                              void* d_out, int out_size, void* d_ws, size_t ws_size,
                              hipStream_t stream)
{
    const int*   src = (const int*)d_in[0];
    const int*   dst = (const int*)d_in[1];
    const float* hc  = (const float*)d_in[2];
    const float* ht  = (const float*)d_in[3];
    const float* hr  = (const float*)d_in[4];
    const float* Wc  = (const float*)d_in[5];
    const float* Wt  = (const float*)d_in[6];
    const float* Wr  = (const float*)d_in[7];
    const float* fw  = (const float*)d_in[8];
    const float* fb  = (const float*)d_in[9];
    const float* W0  = (const float*)d_in[10];
    const float* al0 = (const float*)d_in[11];
    const float* ar0 = (const float*)d_in[12];
    const float* b0  = (const float*)d_in[13];
    const float* W1  = (const float*)d_in[14];
    const float* al1 = (const float*)d_in[15];
    const float* ar1 = (const float*)d_in[16];
    const float* b1  = (const float*)d_in[17];

    // workspace layout (bytes)
    char* ws = (char*)d_ws;
    float* h0    = (float*)(ws);                   // N*64   f32 : 12,800,000 B
    float* feat  = (float*)(ws + 12800000);        // N*256  f32 : 51,200,000 B
    float* el    = (float*)(ws + 64000000);        // N*4    f32 :    800,000 B
    float* er    = (float*)(ws + 64800000);        // N*4    f32 :    800,000 B
    int*   cnt   = (int*)  (ws + 65600000);        // N      i32 :    200,000 B
    int*   offs  = (int*)  (ws + 65800000);        // N+1    i32 :    200,064 B (padded)
    int*   esort = (int*)  (ws + 66000064);        // E      i32 :  3,200,000 B
    if (ws_size < 69200064) return;                // insufficient scratch -> loud failure

    float* outh = (float*)d_out;                   // N*256 final h
    float* atto = outh + (size_t)NN * 256;         // E*4 attention (layer 1)

    // Stage A: trilinear fusion
    fusion_kernel<<<(NN + 31) / 32, 256, 0, stream>>>(hc, ht, hr, Wc, Wt, Wr, fw, fb, h0);

    // CSR by dst
    hipMemsetAsync(cnt, 0, NN * sizeof(int), stream);
    hist_kernel<<<(EE + 255) / 256, 256, 0, stream>>>(dst, cnt);
    scan_kernel<<<1, 1024, 0, stream>>>(cnt, offs);
    hipMemsetAsync(cnt, 0, NN * sizeof(int), stream);
    scatter_kernel<<<(EE + 255) / 256, 256, 0, stream>>>(dst, offs, cnt, esort);

    // GAT layer 0 (no residual, attention not exported); h1 lives in d_out h-region
    gemm_feat<64><<<(NN + 31) / 32, 256, 0, stream>>>(h0, W0, feat);
    elr_kernel<<<(NN * 64 + 255) / 256, 256, 0, stream>>>(feat, al0, ar0, el, er);
    gat_agg<0, 0><<<(NN * 64 + 255) / 256, 256, 0, stream>>>(
        esort, src, offs, feat, el, er, nullptr, b0, outh, nullptr);

    // GAT layer 1 (residual, export attention); output in place over h1
    gemm_feat<256><<<(NN + 31) / 32, 256, 0, stream>>>(outh, W1, feat);
    elr_kernel<<<(NN * 64 + 255) / 256, 256, 0, stream>>>(feat, al1, ar1, el, er);
    gat_agg<1, 1><<<(NN * 64 + 255) / 256, 256, 0, stream>>>(
        esort, src, offs, feat, el, er, outh, b1, outh, atto);
}

// Round 3
// 881.313 us; speedup vs baseline: 1.8254x; 1.8254x over previous
//
#include <hip/hip_runtime.h>
#include <math.h>

#define NN 50000
#define EE 800000
#define NEG 0.2f

using f32x4  = __attribute__((ext_vector_type(4))) float;
using bf16x8 = __attribute__((ext_vector_type(8))) short;

__device__ __forceinline__ float lrelu(float x){ return x > 0.f ? x : NEG*x; }

__device__ __forceinline__ unsigned short f2b(float f){
    unsigned int u = __float_as_uint(f);
    return (unsigned short)((u + 0x7FFFu + ((u >> 16) & 1u)) >> 16);  // RNE
}
__device__ __forceinline__ float b2f(unsigned short h){
    return __uint_as_float(((unsigned int)h) << 16);
}
__device__ __forceinline__ void gld_lds16(const void* g, void* l){
    __builtin_amdgcn_global_load_lds(
        (const __attribute__((address_space(1))) unsigned int*)g,
        (__attribute__((address_space(3))) unsigned int*)l, 16, 0, 0);
}

// ---------------------------------------------------------------------------
// Weight packers: fragment-order bf16.
// Fusion layout: [kc][chunk=r*4+ct][lane][8], K padded with zeros.
//   element: r=chunk>>2, c=(chunk&3)*16+(l&15), k=kc*32+(l>>4)*8+j
// ---------------------------------------------------------------------------
__global__ void pack_w_fusion(const float* __restrict__ W, unsigned short* __restrict__ out,
                              int K, int NKC)
{
    int u = blockIdx.x * blockDim.x + threadIdx.x;
    if (u >= NKC * 16 * 64) return;
    int l = u & 63, chunk = (u >> 6) & 15, kc = u >> 10;
    int r = chunk >> 2, c = (chunk & 3) * 16 + (l & 15);
    int kb = kc * 32 + (l >> 4) * 8;
    bf16x8 v;
#pragma unroll
    for (int j = 0; j < 8; ++j) {
        int k = kb + j;
        v[j] = (short)((k < K) ? f2b(W[((size_t)r * K + k) * 64 + c]) : 0);
    }
    *(bf16x8*)(out + (size_t)u * 8) = v;
}

// GEMM weights: [kc][ct(C/16)][lane][8]; K multiple of 32.
__global__ void pack_w_gemm(const float* __restrict__ W, unsigned short* __restrict__ out,
                            int K, int C)
{
    int NCH = C / 16;
    int total = (K / 32) * NCH * 64;
    int u = blockIdx.x * blockDim.x + threadIdx.x;
    if (u >= total) return;
    int l = u & 63, ch = (u >> 6) % NCH, kc = u / (64 * NCH);
    int c = ch * 16 + (l & 15);
    int kb = kc * 32 + (l >> 4) * 8;
    bf16x8 v;
#pragma unroll
    for (int j = 0; j < 8; ++j)
        v[j] = (short)f2b(W[(size_t)(kb + j) * C + c]);
    *(bf16x8*)(out + (size_t)u * 8) = v;
}

// ---------------------------------------------------------------------------
// Fusion: one GEMM pass (one of hc/ht/hr), MFMA 16x16x32 bf16.
// Block = 64 nodes x 64 cols, 4 waves; wave w owns c-tile w (16 cols), all 4 r.
// A-LDS unit(nf,kg,nodelo) at (nf*64+kg*16+nodelo)*16B -> frag read lane-linear.
// ---------------------------------------------------------------------------
__device__ __forceinline__ void fusion_pass(
    const float* __restrict__ F, const unsigned short* __restrict__ wp,
    int K, int NKC, int nb, int w, int l, int tid,
    unsigned short* ldsA, unsigned short* ldsB, f32x4 (&acc)[4][4])
{
#pragma unroll
    for (int r = 0; r < 4; ++r)
#pragma unroll
        for (int nf = 0; nf < 4; ++nf) acc[r][nf] = f32x4{0.f, 0.f, 0.f, 0.f};

    const int n_l = tid >> 2, kg = tid & 3;
    const int n = nb + n_l;
    const unsigned aoff = (unsigned)(((n_l >> 4) * 64 + kg * 16 + (n_l & 15)) * 8);

    for (int kc = 0; kc < NKC; ++kc) {
        __syncthreads();  // previous compute done before overwrite
        // stage B: 16KB via global_load_lds (wave-uniform dst, per-lane src)
        const unsigned short* wsrc = wp + (size_t)kc * 8192;
#pragma unroll
        for (int i = 0; i < 4; ++i) {
            int ch = w * 4 + i;
            gld_lds16(wsrc + ch * 512 + l * 8, ldsB + ch * 512);
        }
        // stage A: 8 f32 -> 8 bf16 (rows are 4B-aligned only -> scalar loads)
        int kbase = kc * 32 + kg * 8;
        bf16x8 a8;
#pragma unroll
        for (int j = 0; j < 8; ++j) {
            int k = kbase + j;
            float x = (n < NN && k < K) ? F[(size_t)n * K + k] : 0.f;
            a8[j] = (short)f2b(x);
        }
        *(bf16x8*)(ldsA + aoff) = a8;
        __syncthreads();  // staging visible (drains vmcnt+lgkmcnt)
        // compute: 16 MFMA per wave per K-step
        bf16x8 bfr[4];
#pragma unroll
        for (int r = 0; r < 4; ++r)
            bfr[r] = *(const bf16x8*)(ldsB + ((r * 4 + w) * 64 + l) * 8);
#pragma unroll
        for (int nf = 0; nf < 4; ++nf) {
            bf16x8 af = *(const bf16x8*)(ldsA + (nf * 64 + l) * 8);
#pragma unroll
            for (int r = 0; r < 4; ++r)
                acc[r][nf] = __builtin_amdgcn_mfma_f32_16x16x32_bf16(af, bfr[r], acc[r][nf], 0, 0, 0);
        }
    }
}

__global__ __launch_bounds__(256) void fusion_mfma(
    const float* __restrict__ hc, const float* __restrict__ ht, const float* __restrict__ hr,
    const unsigned short* __restrict__ wpc, const unsigned short* __restrict__ wpt,
    const unsigned short* __restrict__ wpr,
    const float* __restrict__ fw, const float* __restrict__ fb,
    unsigned short* __restrict__ h0b)
{
    __shared__ unsigned short ldsA[2048];   // 4KB
    __shared__ unsigned short ldsB[8192];   // 16KB
    const int tid = threadIdx.x, w = tid >> 6, l = tid & 63;
    const int nb = blockIdx.x * 64;

    f32x4 prod[4][4], acc[4][4];
    fusion_pass(hc, wpc, 129, 5, nb, w, l, tid, ldsA, ldsB, acc);
#pragma unroll
    for (int r = 0; r < 4; ++r)
#pragma unroll
        for (int nf = 0; nf < 4; ++nf) prod[r][nf] = acc[r][nf];
    fusion_pass(ht, wpt, 513, 17, nb, w, l, tid, ldsA, ldsB, acc);
#pragma unroll
    for (int r = 0; r < 4; ++r)
#pragma unroll
        for (int nf = 0; nf < 4; ++nf) prod[r][nf] *= acc[r][nf];
    fusion_pass(hr, wpr, 513, 17, nb, w, l, tid, ldsA, ldsB, acc);
#pragma unroll
    for (int r = 0; r < 4; ++r)
#pragma unroll
        for (int nf = 0; nf < 4; ++nf) prod[r][nf] *= acc[r][nf];

    float fw0 = fw[0], fw1 = fw[1], fw2 = fw[2], fw3 = fw[3];
    int c = w * 16 + (l & 15);
    float fbc = fb[c];
#pragma unroll
    for (int nf = 0; nf < 4; ++nf)
#pragma unroll
        for (int q = 0; q < 4; ++q) {
            int n = nb + nf * 16 + (l >> 4) * 4 + q;
            if (n < NN) {
                float v = fbc + fw0 * prod[0][nf][q] + fw1 * prod[1][nf][q]
                              + fw2 * prod[2][nf][q] + fw3 * prod[3][nf][q];
                v = v > 0.f ? v : expm1f(v);
                h0b[(size_t)n * 64 + c] = f2b(v);
            }
        }
}

// ---------------------------------------------------------------------------
// feat GEMM: bf16 A (pre-converted), packed bf16 W, bf16 feat out.
// Block = 64 nodes; wave w owns c-tiles {4w..4w+3} of C=256.
// ---------------------------------------------------------------------------
template<int K>
__global__ __launch_bounds__(256) void gemm_mfma(
    const unsigned short* __restrict__ Ab, const unsigned short* __restrict__ wp,
    unsigned short* __restrict__ featb)
{
    constexpr int NKC = K / 32;
    __shared__ unsigned short ldsA[2048];
    __shared__ unsigned short ldsB[8192];
    const int tid = threadIdx.x, w = tid >> 6, l = tid & 63;
    const int nb = blockIdx.x * 64;

    f32x4 acc[4][4];  // [i = ct within wave][nf]
#pragma unroll
    for (int i = 0; i < 4; ++i)
#pragma unroll
        for (int nf = 0; nf < 4; ++nf) acc[i][nf] = f32x4{0.f, 0.f, 0.f, 0.f};

    int arow = nb + w * 16 + (l & 15);
    if (arow >= NN) arow = NN - 1;  // clamp: padded rows computed but never stored

    for (int kc = 0; kc < NKC; ++kc) {
        __syncthreads();
        // stage A: wave w stages node-group w (1KB)
        gld_lds16(Ab + (size_t)arow * K + kc * 32 + (l >> 4) * 8, ldsA + w * 512);
        // stage B: 16KB
#pragma unroll
        for (int i = 0; i < 4; ++i) {
            int ch = w * 4 + i;
            gld_lds16(wp + (size_t)kc * 8192 + ch * 512 + l * 8, ldsB + ch * 512);
        }
        __syncthreads();
        bf16x8 bfr[4];
#pragma unroll
        for (int i = 0; i < 4; ++i)
            bfr[i] = *(const bf16x8*)(ldsB + ((w * 4 + i) * 64 + l) * 8);
#pragma unroll
        for (int nf = 0; nf < 4; ++nf) {
            bf16x8 af = *(const bf16x8*)(ldsA + (nf * 64 + l) * 8);
#pragma unroll
            for (int i = 0; i < 4; ++i)
                acc[i][nf] = __builtin_amdgcn_mfma_f32_16x16x32_bf16(af, bfr[i], acc[i][nf], 0, 0, 0);
        }
    }
#pragma unroll
    for (int i = 0; i < 4; ++i) {
        int c = (w * 4 + i) * 16 + (l & 15);
#pragma unroll
        for (int nf = 0; nf < 4; ++nf)
#pragma unroll
            for (int q = 0; q < 4; ++q) {
                int n = nb + nf * 16 + (l >> 4) * 4 + q;
                if (n < NN) featb[(size_t)n * 256 + c] = f2b(acc[i][nf][q]);
            }
    }
}

// ---------------------------------------------------------------------------
// el/er: one wave per node, bf16 feat input.
// ---------------------------------------------------------------------------
__global__ __launch_bounds__(256) void elr_kernel(
    const unsigned short* __restrict__ featb,
    const float* __restrict__ al, const float* __restrict__ ar,
    float* __restrict__ el, float* __restrict__ er)
{
    int wid = (int)((blockIdx.x * (size_t)blockDim.x + threadIdx.x) >> 6);
    int lane = threadIdx.x & 63;
    if (wid >= NN) return;
    float elh[4], erh[4];
#pragma unroll
    for (int h = 0; h < 4; ++h) {
        float x = b2f(featb[(size_t)wid * 256 + h * 64 + lane]);
        elh[h] = x * al[h * 64 + lane];
        erh[h] = x * ar[h * 64 + lane];
    }
#pragma unroll
    for (int off = 32; off; off >>= 1) {
#pragma unroll
        for (int h = 0; h < 4; ++h) {
            elh[h] += __shfl_xor(elh[h], off);
            erh[h] += __shfl_xor(erh[h], off);
        }
    }
    if (lane == 0) {
        *(float4*)(el + (size_t)wid * 4) = make_float4(elh[0], elh[1], elh[2], elh[3]);
        *(float4*)(er + (size_t)wid * 4) = make_float4(erh[0], erh[1], erh[2], erh[3]);
    }
}

// ---------------------------------------------------------------------------
// CSR build
// ---------------------------------------------------------------------------
__global__ void hist_kernel(const int* __restrict__ dst, int* __restrict__ cnt)
{
    int e = blockIdx.x * blockDim.x + threadIdx.x;
    if (e < EE) atomicAdd(&cnt[dst[e]], 1);
}

__global__ __launch_bounds__(1024) void scan_kernel(const int* __restrict__ cnt, int* __restrict__ offs)
{
    __shared__ int tmp[1024];
    const int t = threadIdx.x;
    const int C = (NN + 1023) / 1024;
    int lo = t * C, hi = min(lo + C, NN);
    int s = 0;
    for (int i = lo; i < hi; ++i) s += cnt[i];
    tmp[t] = s;
    __syncthreads();
    for (int off = 1; off < 1024; off <<= 1) {
        int v = (t >= off) ? tmp[t - off] : 0;
        __syncthreads();
        tmp[t] += v;
        __syncthreads();
    }
    int run = (t == 0) ? 0 : tmp[t - 1];
    for (int i = lo; i < hi; ++i) { offs[i] = run; run += cnt[i]; }
    if (t == 1023) offs[NN] = tmp[1023];
}

__global__ void scatter_kernel(const int* __restrict__ dst, const int* __restrict__ offs,
                               int* __restrict__ cur, int* __restrict__ esort)
{
    int e = blockIdx.x * blockDim.x + threadIdx.x;
    if (e < EE) {
        int d = dst[e];
        int p = offs[d] + atomicAdd(&cur[d], 1);
        esort[p] = e;
    }
}

// ---------------------------------------------------------------------------
// Per-dst softmax + aggregation. One wave per dst node. bf16 feat.
// ---------------------------------------------------------------------------
template <int RESID, int WATT, int WB16>
__global__ __launch_bounds__(256) void gat_agg(
    const int* __restrict__ esort, const int* __restrict__ src, const int* __restrict__ offs,
    const unsigned short* __restrict__ featb,
    const float* __restrict__ el, const float* __restrict__ er,
    const float* __restrict__ resid, const float* __restrict__ bias,
    float* __restrict__ out, unsigned short* __restrict__ outb, float* __restrict__ att)
{
    int n = (int)((blockIdx.x * (size_t)blockDim.x + threadIdx.x) >> 6);
    int lane = threadIdx.x & 63;
    if (n >= NN) return;
    int s0 = offs[n], s1 = offs[n + 1];
    float4 e4 = *(const float4*)(er + (size_t)n * 4);

    float m0 = -1e30f, m1 = -1e30f, m2 = -1e30f, m3 = -1e30f;
    for (int p = s0 + lane; p < s1; p += 64) {
        int e = esort[p]; int s = src[e];
        float4 l4 = *(const float4*)(el + (size_t)s * 4);
        m0 = fmaxf(m0, lrelu(l4.x + e4.x));
        m1 = fmaxf(m1, lrelu(l4.y + e4.y));
        m2 = fmaxf(m2, lrelu(l4.z + e4.z));
        m3 = fmaxf(m3, lrelu(l4.w + e4.w));
    }
#pragma unroll
    for (int off = 32; off; off >>= 1) {
        m0 = fmaxf(m0, __shfl_xor(m0, off));
        m1 = fmaxf(m1, __shfl_xor(m1, off));
        m2 = fmaxf(m2, __shfl_xor(m2, off));
        m3 = fmaxf(m3, __shfl_xor(m3, off));
    }

    float z0 = 0.f, z1 = 0.f, z2 = 0.f, z3 = 0.f;
    for (int p = s0 + lane; p < s1; p += 64) {
        int e = esort[p]; int s = src[e];
        float4 l4 = *(const float4*)(el + (size_t)s * 4);
        z0 += expf(lrelu(l4.x + e4.x) - m0);
        z1 += expf(lrelu(l4.y + e4.y) - m1);
        z2 += expf(lrelu(l4.z + e4.z) - m2);
        z3 += expf(lrelu(l4.w + e4.w) - m3);
    }
#pragma unroll
    for (int off = 32; off; off >>= 1) {
        z0 += __shfl_xor(z0, off);
        z1 += __shfl_xor(z1, off);
        z2 += __shfl_xor(z2, off);
        z3 += __shfl_xor(z3, off);
    }
    float i0 = z0 > 0.f ? 1.f / z0 : 0.f;
    float i1 = z1 > 0.f ? 1.f / z1 : 0.f;
    float i2 = z2 > 0.f ? 1.f / z2 : 0.f;
    float i3 = z3 > 0.f ? 1.f / z3 : 0.f;

    float a0 = 0.f, a1 = 0.f, a2 = 0.f, a3 = 0.f;
    for (int p = s0; p < s1; ++p) {
        int e = esort[p]; int s = src[e];
        float4 l4 = *(const float4*)(el + (size_t)s * 4);
        float w0 = expf(lrelu(l4.x + e4.x) - m0) * i0;
        float w1 = expf(lrelu(l4.y + e4.y) - m1) * i1;
        float w2 = expf(lrelu(l4.z + e4.z) - m2) * i2;
        float w3 = expf(lrelu(l4.w + e4.w) - m3) * i3;
        const unsigned short* fp = featb + (size_t)s * 256;
        a0 += w0 * b2f(fp[lane]);
        a1 += w1 * b2f(fp[64 + lane]);
        a2 += w2 * b2f(fp[128 + lane]);
        a3 += w3 * b2f(fp[192 + lane]);
        if (WATT && lane < 4) {
            float wl = lane == 0 ? w0 : lane == 1 ? w1 : lane == 2 ? w2 : w3;
            att[(size_t)e * 4 + lane] = wl;
        }
    }
    float o0 = a0 + bias[lane];
    float o1 = a1 + bias[64 + lane];
    float o2 = a2 + bias[128 + lane];
    float o3 = a3 + bias[192 + lane];
    if (RESID) {
        const float* rp = resid + (size_t)n * 256;
        o0 += rp[lane];
        o1 += rp[64 + lane];
        o2 += rp[128 + lane];
        o3 += rp[192 + lane];
    }
    float* op = out + (size_t)n * 256;
    op[lane] = o0;
    op[64 + lane] = o1;
    op[128 + lane] = o2;
    op[192 + lane] = o3;
    if (WB16) {
        unsigned short* ob = outb + (size_t)n * 256;
        ob[lane] = f2b(o0);
        ob[64 + lane] = f2b(o1);
        ob[128 + lane] = f2b(o2);
        ob[192 + lane] = f2b(o3);
    }
}

// ---------------------------------------------------------------------------
extern "C" void kernel_launch(void* const* d_in, const int* in_sizes, int n_in,
                              void* d_out, int out_size, void* d_ws, size_t ws_size,
                              hipStream_t stream)
{
    const int*   src = (const int*)d_in[0];
    const int*   dst = (const int*)d_in[1];
    const float* hc  = (const float*)d_in[2];
    const float* ht  = (const float*)d_in[3];
    const float* hr  = (const float*)d_in[4];
    const float* Wc  = (const float*)d_in[5];
    const float* Wt  = (const float*)d_in[6];
    const float* Wr  = (const float*)d_in[7];
    const float* fw  = (const float*)d_in[8];
    const float* fb  = (const float*)d_in[9];
    const float* W0  = (const float*)d_in[10];
    const float* al0 = (const float*)d_in[11];
    const float* ar0 = (const float*)d_in[12];
    const float* b0  = (const float*)d_in[13];
    const float* W1  = (const float*)d_in[14];
    const float* al1 = (const float*)d_in[15];
    const float* ar1 = (const float*)d_in[16];
    const float* b1  = (const float*)d_in[17];

    // workspace layout (bytes)
    char* ws = (char*)d_ws;
    unsigned short* h0b   = (unsigned short*)(ws);               // N*64  bf16 :  6,400,000
    unsigned short* h1b   = (unsigned short*)(ws + 6400000);     // N*256 bf16 : 25,600,000
    unsigned short* featb = (unsigned short*)(ws + 32000000);    // N*256 bf16 : 25,600,000
    float* el    = (float*)(ws + 57600000);                      //    800,000
    float* er    = (float*)(ws + 58400000);                      //    800,000
    int*   cnt   = (int*)  (ws + 59200000);                      //    200,000
    int*   offs  = (int*)  (ws + 59400000);                      //    200,004
    int*   esort = (int*)  (ws + 59600128);                      //  3,200,000
    unsigned short* wpc = (unsigned short*)(ws + 62800128);      //  5*16KB =  81,920
    unsigned short* wpt = (unsigned short*)(ws + 62882048);      // 17*16KB = 278,528
    unsigned short* wpr = (unsigned short*)(ws + 63160576);      // 17*16KB = 278,528
    unsigned short* wp0 = (unsigned short*)(ws + 63439104);      //  2*16KB =  32,768
    unsigned short* wp1 = (unsigned short*)(ws + 63471872);      //  8*16KB = 131,072
    if (ws_size < 63602944ull) return;                           // end of layout

    float* outh = (float*)d_out;                   // N*256 final h
    float* atto = outh + (size_t)NN * 256;         // E*4 attention (layer 1)

    // weight packing (fragment-order bf16)
    pack_w_fusion<<<(5 * 16 * 64 + 255) / 256, 256, 0, stream>>>(Wc, wpc, 129, 5);
    pack_w_fusion<<<(17 * 16 * 64 + 255) / 256, 256, 0, stream>>>(Wt, wpt, 513, 17);
    pack_w_fusion<<<(17 * 16 * 64 + 255) / 256, 256, 0, stream>>>(Wr, wpr, 513, 17);
    pack_w_gemm<<<(2 * 16 * 64 + 255) / 256, 256, 0, stream>>>(W0, wp0, 64, 256);
    pack_w_gemm<<<(8 * 16 * 64 + 255) / 256, 256, 0, stream>>>(W1, wp1, 256, 256);

    // Stage A: trilinear fusion (MFMA)
    fusion_mfma<<<(NN + 63) / 64, 256, 0, stream>>>(hc, ht, hr, wpc, wpt, wpr, fw, fb, h0b);

    // CSR by dst
    hipMemsetAsync(cnt, 0, NN * sizeof(int), stream);
    hist_kernel<<<(EE + 255) / 256, 256, 0, stream>>>(dst, cnt);
    scan_kernel<<<1, 1024, 0, stream>>>(cnt, offs);
    hipMemsetAsync(cnt, 0, NN * sizeof(int), stream);
    scatter_kernel<<<(EE + 255) / 256, 256, 0, stream>>>(dst, offs, cnt, esort);

    // GAT layer 0: out0 (f32) -> d_out h-region, bf16 copy -> h1b
    gemm_mfma<64><<<(NN + 63) / 64, 256, 0, stream>>>(h0b, wp0, featb);
    elr_kernel<<<(NN * 64 + 255) / 256, 256, 0, stream>>>(featb, al0, ar0, el, er);
    gat_agg<0, 0, 1><<<(NN * 64 + 255) / 256, 256, 0, stream>>>(
        esort, src, offs, featb, el, er, nullptr, b0, outh, h1b, nullptr);

    // GAT layer 1: residual, export attention; output in place over out0
    gemm_mfma<256><<<(NN + 63) / 64, 256, 0, stream>>>(h1b, wp1, featb);
    elr_kernel<<<(NN * 64 + 255) / 256, 256, 0, stream>>>(featb, al1, ar1, el, er);
    gat_agg<1, 1, 0><<<(NN * 64 + 255) / 256, 256, 0, stream>>>(
        esort, src, offs, featb, el, er, outh, b1, outh, nullptr, atto);
}

// Round 4
// 805.825 us; speedup vs baseline: 1.9963x; 1.0937x over previous
//
#include <hip/hip_runtime.h>
#include <math.h>

#define NN 50000
#define EE 800000
#define NEG 0.2f

using f32x4  = __attribute__((ext_vector_type(4))) float;
using bf16x8 = __attribute__((ext_vector_type(8))) short;

__device__ __forceinline__ float lrelu(float x){ return x > 0.f ? x : NEG*x; }

__device__ __forceinline__ unsigned short f2b(float f){
    unsigned int u = __float_as_uint(f);
    return (unsigned short)((u + 0x7FFFu + ((u >> 16) & 1u)) >> 16);  // RNE
}
__device__ __forceinline__ float b2f(unsigned short h){
    return __uint_as_float(((unsigned int)h) << 16);
}
__device__ __forceinline__ void gld_lds16(const void* g, void* l){
    __builtin_amdgcn_global_load_lds(
        (const __attribute__((address_space(1))) unsigned int*)g,
        (__attribute__((address_space(3))) unsigned int*)l, 16, 0, 0);
}

// ---------------------------------------------------------------------------
// Weight packers (fragment-order bf16).
// Fusion: [kc][chunk=r*4+ct][lane][8]; only k < Kp (ones-row handled via init).
// ---------------------------------------------------------------------------
__global__ void pack_w_fusion(const float* __restrict__ W, unsigned short* __restrict__ out,
                              int K, int NKC)   // K = true K (129/513), NKC = (K-1)/32
{
    int u = blockIdx.x * blockDim.x + threadIdx.x;
    if (u >= NKC * 16 * 64) return;
    int l = u & 63, chunk = (u >> 6) & 15, kc = u >> 10;
    int r = chunk >> 2, c = (chunk & 3) * 16 + (l & 15);
    int kb = kc * 32 + (l >> 4) * 8;
    bf16x8 v;
#pragma unroll
    for (int j = 0; j < 8; ++j)
        v[j] = (short)f2b(W[((size_t)r * K + kb + j) * 64 + c]);
    *(bf16x8*)(out + (size_t)u * 8) = v;
}

// GEMM weights: [kc][ct(C/16)][lane][8]; K multiple of 32.
__global__ void pack_w_gemm(const float* __restrict__ W, unsigned short* __restrict__ out,
                            int K, int C)
{
    int NCH = C / 16;
    int total = (K / 32) * NCH * 64;
    int u = blockIdx.x * blockDim.x + threadIdx.x;
    if (u >= total) return;
    int l = u & 63, ch = (u >> 6) % NCH, kc = u / (64 * NCH);
    int c = ch * 16 + (l & 15);
    int kb = kc * 32 + (l >> 4) * 8;
    bf16x8 v;
#pragma unroll
    for (int j = 0; j < 8; ++j)
        v[j] = (short)f2b(W[(size_t)(kb + j) * C + c]);
    *(bf16x8*)(out + (size_t)u * 8) = v;
}

// ---------------------------------------------------------------------------
// Fusion pass: double-buffered, 1 barrier per K-chunk.
// Block = 64 nodes x 64 cols, 4 waves; wave w owns col-tile w, all 4 r.
// acc initialized from the ones-column row W[r][K-1][c] (exact f32).
// Thread tid stages LDS unit tid (linear 16B -> conflict-free ds_write):
//   unit u: node = nb + ((u>>6)<<4) + (u&15), k = kc*32 + ((u>>4)&3)*8 + j.
// ---------------------------------------------------------------------------
__device__ __forceinline__ void fusion_pass_db(
    const float* __restrict__ F, const unsigned short* __restrict__ wp,
    const float* __restrict__ W, int K, int NKC,
    int nb, int w, int l, int tid,
    unsigned short* ldsA, unsigned short* ldsB, f32x4 (&acc)[4][4])
{
    const int c = w * 16 + (l & 15);
#pragma unroll
    for (int r = 0; r < 4; ++r) {
        float wi = W[((size_t)r * K + (K - 1)) * 64 + c];
        f32x4 v = {wi, wi, wi, wi};
#pragma unroll
        for (int nf = 0; nf < 4; ++nf) acc[r][nf] = v;
    }
    int n = nb + ((tid >> 6) << 4) + (tid & 15);
    if (n >= NN) n = NN - 1;                       // clamp: rows >= NN unused
    const int kg = (tid >> 4) & 3;
    const float* fbase = F + (size_t)n * K + kg * 8;

    // prologue: stage chunk 0 into buffer 0
    {
#pragma unroll
        for (int i = 0; i < 4; ++i)
            gld_lds16(wp + (size_t)(w * 4 + i) * 512 + l * 8, ldsB + (w * 4 + i) * 512);
        bf16x8 a8;
#pragma unroll
        for (int j = 0; j < 8; ++j) a8[j] = (short)f2b(fbase[j]);
        *(bf16x8*)(ldsA + tid * 8) = a8;
    }
    __syncthreads();

    for (int t = 0; t < NKC; ++t) {
        const int cur = t & 1;
        unsigned short* lA = ldsA + cur * 2048;
        unsigned short* lB = ldsB + cur * 8192;
        unsigned short* nA = ldsA + (cur ^ 1) * 2048;
        unsigned short* nB = ldsB + (cur ^ 1) * 8192;
        const bool more = (t + 1 < NKC);
        float a[8];
        if (more) {
            const unsigned short* wsrc = wp + (size_t)(t + 1) * 8192;
#pragma unroll
            for (int i = 0; i < 4; ++i)
                gld_lds16(wsrc + (w * 4 + i) * 512 + l * 8, nB + (w * 4 + i) * 512);
            const float* fp = fbase + (t + 1) * 32;
#pragma unroll
            for (int j = 0; j < 8; ++j) a[j] = fp[j];
        }
        // compute chunk t
        bf16x8 bfr[4];
#pragma unroll
        for (int r = 0; r < 4; ++r)
            bfr[r] = *(const bf16x8*)(lB + ((r * 4 + w) * 64 + l) * 8);
#pragma unroll
        for (int nf = 0; nf < 4; ++nf) {
            bf16x8 af = *(const bf16x8*)(lA + (nf * 64 + l) * 8);
#pragma unroll
            for (int r = 0; r < 4; ++r)
                acc[r][nf] = __builtin_amdgcn_mfma_f32_16x16x32_bf16(af, bfr[r], acc[r][nf], 0, 0, 0);
        }
        if (more) {
            bf16x8 a8;
#pragma unroll
            for (int j = 0; j < 8; ++j) a8[j] = (short)f2b(a[j]);
            *(bf16x8*)(nA + tid * 8) = a8;
        }
        __syncthreads();
    }
}

__global__ __launch_bounds__(256) void fusion_mfma(
    const float* __restrict__ hc, const float* __restrict__ ht, const float* __restrict__ hr,
    const unsigned short* __restrict__ wpc, const unsigned short* __restrict__ wpt,
    const unsigned short* __restrict__ wpr,
    const float* __restrict__ Wc, const float* __restrict__ Wt, const float* __restrict__ Wr,
    const float* __restrict__ fw, const float* __restrict__ fb,
    unsigned short* __restrict__ h0b)
{
    __shared__ unsigned short ldsA[4096];    // 2 x 4KB
    __shared__ unsigned short ldsB[16384];   // 2 x 16KB
    const int tid = threadIdx.x, w = tid >> 6, l = tid & 63;
    const int nb = blockIdx.x * 64;

    f32x4 prod[4][4], acc[4][4];
    fusion_pass_db(hc, wpc, Wc, 129, 4, nb, w, l, tid, ldsA, ldsB, acc);
#pragma unroll
    for (int r = 0; r < 4; ++r)
#pragma unroll
        for (int nf = 0; nf < 4; ++nf) prod[r][nf] = acc[r][nf];
    fusion_pass_db(ht, wpt, Wt, 513, 16, nb, w, l, tid, ldsA, ldsB, acc);
#pragma unroll
    for (int r = 0; r < 4; ++r)
#pragma unroll
        for (int nf = 0; nf < 4; ++nf) prod[r][nf] *= acc[r][nf];
    fusion_pass_db(hr, wpr, Wr, 513, 16, nb, w, l, tid, ldsA, ldsB, acc);
#pragma unroll
    for (int r = 0; r < 4; ++r)
#pragma unroll
        for (int nf = 0; nf < 4; ++nf) prod[r][nf] *= acc[r][nf];

    float fw0 = fw[0], fw1 = fw[1], fw2 = fw[2], fw3 = fw[3];
    int c = w * 16 + (l & 15);
    float fbc = fb[c];
#pragma unroll
    for (int nf = 0; nf < 4; ++nf)
#pragma unroll
        for (int q = 0; q < 4; ++q) {
            int n = nb + nf * 16 + (l >> 4) * 4 + q;
            if (n < NN) {
                float v = fbc + fw0 * prod[0][nf][q] + fw1 * prod[1][nf][q]
                              + fw2 * prod[2][nf][q] + fw3 * prod[3][nf][q];
                v = v > 0.f ? v : expm1f(v);
                h0b[(size_t)n * 64 + c] = f2b(v);
            }
        }
}

// ---------------------------------------------------------------------------
// feat GEMM: bf16 A, packed bf16 W, bf16 out. Double-buffered, 1 barrier/chunk.
// ---------------------------------------------------------------------------
template<int K>
__global__ __launch_bounds__(256) void gemm_mfma(
    const unsigned short* __restrict__ Ab, const unsigned short* __restrict__ wp,
    unsigned short* __restrict__ featb)
{
    constexpr int NKC = K / 32;
    __shared__ unsigned short ldsA[4096];
    __shared__ unsigned short ldsB[16384];
    const int tid = threadIdx.x, w = tid >> 6, l = tid & 63;
    const int nb = blockIdx.x * 64;

    f32x4 acc[4][4];
#pragma unroll
    for (int i = 0; i < 4; ++i)
#pragma unroll
        for (int nf = 0; nf < 4; ++nf) acc[i][nf] = f32x4{0.f, 0.f, 0.f, 0.f};

    int arow = nb + w * 16 + (l & 15);
    if (arow >= NN) arow = NN - 1;

    // prologue: chunk 0 -> buffer 0
    gld_lds16(Ab + (size_t)arow * K + (l >> 4) * 8, ldsA + w * 512);
#pragma unroll
    for (int i = 0; i < 4; ++i)
        gld_lds16(wp + (size_t)(w * 4 + i) * 512 + l * 8, ldsB + (w * 4 + i) * 512);
    __syncthreads();

    for (int t = 0; t < NKC; ++t) {
        const int cur = t & 1;
        unsigned short* lA = ldsA + cur * 2048;
        unsigned short* lB = ldsB + cur * 8192;
        if (t + 1 < NKC) {
            unsigned short* nA = ldsA + (cur ^ 1) * 2048;
            unsigned short* nB = ldsB + (cur ^ 1) * 8192;
            gld_lds16(Ab + (size_t)arow * K + (t + 1) * 32 + (l >> 4) * 8, nA + w * 512);
            const unsigned short* wsrc = wp + (size_t)(t + 1) * 8192;
#pragma unroll
            for (int i = 0; i < 4; ++i)
                gld_lds16(wsrc + (w * 4 + i) * 512 + l * 8, nB + (w * 4 + i) * 512);
        }
        bf16x8 bfr[4];
#pragma unroll
        for (int i = 0; i < 4; ++i)
            bfr[i] = *(const bf16x8*)(lB + ((w * 4 + i) * 64 + l) * 8);
#pragma unroll
        for (int nf = 0; nf < 4; ++nf) {
            bf16x8 af = *(const bf16x8*)(lA + (nf * 64 + l) * 8);
#pragma unroll
            for (int i = 0; i < 4; ++i)
                acc[i][nf] = __builtin_amdgcn_mfma_f32_16x16x32_bf16(af, bfr[i], acc[i][nf], 0, 0, 0);
        }
        __syncthreads();
    }
#pragma unroll
    for (int i = 0; i < 4; ++i) {
        int c = (w * 4 + i) * 16 + (l & 15);
#pragma unroll
        for (int nf = 0; nf < 4; ++nf)
#pragma unroll
            for (int q = 0; q < 4; ++q) {
                int n = nb + nf * 16 + (l >> 4) * 4 + q;
                if (n < NN) featb[(size_t)n * 256 + c] = f2b(acc[i][nf][q]);
            }
    }
}

// ---------------------------------------------------------------------------
// el/er: one wave per node, bf16 feat input.
// ---------------------------------------------------------------------------
__global__ __launch_bounds__(256) void elr_kernel(
    const unsigned short* __restrict__ featb,
    const float* __restrict__ al, const float* __restrict__ ar,
    float* __restrict__ el, float* __restrict__ er)
{
    int wid = (int)((blockIdx.x * (size_t)blockDim.x + threadIdx.x) >> 6);
    int lane = threadIdx.x & 63;
    if (wid >= NN) return;
    float elh[4], erh[4];
#pragma unroll
    for (int h = 0; h < 4; ++h) {
        float x = b2f(featb[(size_t)wid * 256 + h * 64 + lane]);
        elh[h] = x * al[h * 64 + lane];
        erh[h] = x * ar[h * 64 + lane];
    }
#pragma unroll
    for (int off = 32; off; off >>= 1) {
#pragma unroll
        for (int h = 0; h < 4; ++h) {
            elh[h] += __shfl_xor(elh[h], off);
            erh[h] += __shfl_xor(erh[h], off);
        }
    }
    if (lane == 0) {
        *(float4*)(el + (size_t)wid * 4) = make_float4(elh[0], elh[1], elh[2], elh[3]);
        *(float4*)(er + (size_t)wid * 4) = make_float4(erh[0], erh[1], erh[2], erh[3]);
    }
}

// ---------------------------------------------------------------------------
// CSR build
// ---------------------------------------------------------------------------
__global__ void hist_kernel(const int* __restrict__ dst, int* __restrict__ cnt)
{
    int e = blockIdx.x * blockDim.x + threadIdx.x;
    if (e < EE) atomicAdd(&cnt[dst[e]], 1);
}

__global__ __launch_bounds__(1024) void scan_kernel(const int* __restrict__ cnt, int* __restrict__ offs)
{
    __shared__ int tmp[1024];
    const int t = threadIdx.x;
    const int C = (NN + 1023) / 1024;
    int lo = t * C, hi = min(lo + C, NN);
    int s = 0;
    for (int i = lo; i < hi; ++i) s += cnt[i];
    tmp[t] = s;
    __syncthreads();
    for (int off = 1; off < 1024; off <<= 1) {
        int v = (t >= off) ? tmp[t - off] : 0;
        __syncthreads();
        tmp[t] += v;
        __syncthreads();
    }
    int run = (t == 0) ? 0 : tmp[t - 1];
    for (int i = lo; i < hi; ++i) { offs[i] = run; run += cnt[i]; }
    if (t == 1023) offs[NN] = tmp[1023];
}

__global__ void scatter_kernel(const int* __restrict__ dst, const int* __restrict__ offs,
                               int* __restrict__ cur, int* __restrict__ esort)
{
    int e = blockIdx.x * blockDim.x + threadIdx.x;
    if (e < EE) {
        int d = dst[e];
        int p = offs[d] + atomicAdd(&cur[d], 1);
        esort[p] = e;
    }
}

// ---------------------------------------------------------------------------
// edge_prep: CSR-ordered logits eesort[p] = lrelu(el[src[e]] + er[dst[e]]).
// ---------------------------------------------------------------------------
__global__ void edge_prep(const int* __restrict__ esort, const int* __restrict__ src,
                          const int* __restrict__ dst,
                          const float* __restrict__ el, const float* __restrict__ er,
                          float4* __restrict__ eesort)
{
    int p = blockIdx.x * blockDim.x + threadIdx.x;
    if (p >= EE) return;
    int e = esort[p];
    int s = src[e], d = dst[e];
    float4 l4 = *(const float4*)(el + (size_t)s * 4);
    float4 r4 = *(const float4*)(er + (size_t)d * 4);
    eesort[p] = make_float4(lrelu(l4.x + r4.x), lrelu(l4.y + r4.y),
                            lrelu(l4.z + r4.z), lrelu(l4.w + r4.w));
}

// ---------------------------------------------------------------------------
// Per-dst softmax + aggregation, coalesced logit stream. One wave per node.
// WMZ: store per-node (max, 1/z) for att_final. WB16: also store bf16 out.
// ---------------------------------------------------------------------------
template <int RESID, int WMZ, int WB16>
__global__ __launch_bounds__(256) void gat_agg(
    const int* __restrict__ esort, const int* __restrict__ src, const int* __restrict__ offs,
    const unsigned short* __restrict__ featb, const float4* __restrict__ eesort,
    const float* __restrict__ resid, const float* __restrict__ bias,
    float* __restrict__ out, unsigned short* __restrict__ outb,
    float4* __restrict__ mbuf, float4* __restrict__ zbuf)
{
    int n = (int)((blockIdx.x * (size_t)blockDim.x + threadIdx.x) >> 6);
    int lane = threadIdx.x & 63;
    if (n >= NN) return;
    int s0 = offs[n], s1 = offs[n + 1];

    float m0 = -1e30f, m1 = -1e30f, m2 = -1e30f, m3 = -1e30f;
    for (int p = s0 + lane; p < s1; p += 64) {
        float4 v = eesort[p];
        m0 = fmaxf(m0, v.x); m1 = fmaxf(m1, v.y);
        m2 = fmaxf(m2, v.z); m3 = fmaxf(m3, v.w);
    }
#pragma unroll
    for (int off = 32; off; off >>= 1) {
        m0 = fmaxf(m0, __shfl_xor(m0, off));
        m1 = fmaxf(m1, __shfl_xor(m1, off));
        m2 = fmaxf(m2, __shfl_xor(m2, off));
        m3 = fmaxf(m3, __shfl_xor(m3, off));
    }

    float z0 = 0.f, z1 = 0.f, z2 = 0.f, z3 = 0.f;
    for (int p = s0 + lane; p < s1; p += 64) {
        float4 v = eesort[p];
        z0 += expf(v.x - m0); z1 += expf(v.y - m1);
        z2 += expf(v.z - m2); z3 += expf(v.w - m3);
    }
#pragma unroll
    for (int off = 32; off; off >>= 1) {
        z0 += __shfl_xor(z0, off);
        z1 += __shfl_xor(z1, off);
        z2 += __shfl_xor(z2, off);
        z3 += __shfl_xor(z3, off);
    }
    float i0 = z0 > 0.f ? 1.f / z0 : 0.f;
    float i1 = z1 > 0.f ? 1.f / z1 : 0.f;
    float i2 = z2 > 0.f ? 1.f / z2 : 0.f;
    float i3 = z3 > 0.f ? 1.f / z3 : 0.f;
    if (WMZ && lane == 0) {
        mbuf[n] = make_float4(m0, m1, m2, m3);
        zbuf[n] = make_float4(i0, i1, i2, i3);
    }

    float a0 = 0.f, a1 = 0.f, a2 = 0.f, a3 = 0.f;
    for (int p = s0; p < s1; ++p) {
        float4 v = eesort[p];
        int s = src[esort[p]];
        float w0 = expf(v.x - m0) * i0;
        float w1 = expf(v.y - m1) * i1;
        float w2 = expf(v.z - m2) * i2;
        float w3 = expf(v.w - m3) * i3;
        const unsigned short* fp = featb + (size_t)s * 256;
        a0 += w0 * b2f(fp[lane]);
        a1 += w1 * b2f(fp[64 + lane]);
        a2 += w2 * b2f(fp[128 + lane]);
        a3 += w3 * b2f(fp[192 + lane]);
    }
    float o0 = a0 + bias[lane];
    float o1 = a1 + bias[64 + lane];
    float o2 = a2 + bias[128 + lane];
    float o3 = a3 + bias[192 + lane];
    if (RESID) {
        const float* rp = resid + (size_t)n * 256;
        o0 += rp[lane];
        o1 += rp[64 + lane];
        o2 += rp[128 + lane];
        o3 += rp[192 + lane];
    }
    float* op = out + (size_t)n * 256;
    op[lane] = o0;
    op[64 + lane] = o1;
    op[128 + lane] = o2;
    op[192 + lane] = o3;
    if (WB16) {
        unsigned short* ob = outb + (size_t)n * 256;
        ob[lane] = f2b(o0);
        ob[64 + lane] = f2b(o1);
        ob[128 + lane] = f2b(o2);
        ob[192 + lane] = f2b(o3);
    }
}

// ---------------------------------------------------------------------------
// att_final: att[e] = exp(lrelu(el[src]+er[dst]) - m[dst]) / z[dst]
// (recomputes the logit exactly as edge_prep; writes the d_out att region)
// ---------------------------------------------------------------------------
__global__ void att_final(const int* __restrict__ src, const int* __restrict__ dst,
                          const float* __restrict__ el, const float* __restrict__ er,
                          const float4* __restrict__ mbuf, const float4* __restrict__ zbuf,
                          float4* __restrict__ att)
{
    int e = blockIdx.x * blockDim.x + threadIdx.x;
    if (e >= EE) return;
    int s = src[e], d = dst[e];
    float4 l4 = *(const float4*)(el + (size_t)s * 4);
    float4 r4 = *(const float4*)(er + (size_t)d * 4);
    float4 m4 = mbuf[d], zi = zbuf[d];
    att[e] = make_float4(expf(lrelu(l4.x + r4.x) - m4.x) * zi.x,
                         expf(lrelu(l4.y + r4.y) - m4.y) * zi.y,
                         expf(lrelu(l4.z + r4.z) - m4.z) * zi.z,
                         expf(lrelu(l4.w + r4.w) - m4.w) * zi.w);
}

// ---------------------------------------------------------------------------
extern "C" void kernel_launch(void* const* d_in, const int* in_sizes, int n_in,
                              void* d_out, int out_size, void* d_ws, size_t ws_size,
                              hipStream_t stream)
{
    const int*   src = (const int*)d_in[0];
    const int*   dst = (const int*)d_in[1];
    const float* hc  = (const float*)d_in[2];
    const float* ht  = (const float*)d_in[3];
    const float* hr  = (const float*)d_in[4];
    const float* Wc  = (const float*)d_in[5];
    const float* Wt  = (const float*)d_in[6];
    const float* Wr  = (const float*)d_in[7];
    const float* fw  = (const float*)d_in[8];
    const float* fb  = (const float*)d_in[9];
    const float* W0  = (const float*)d_in[10];
    const float* al0 = (const float*)d_in[11];
    const float* ar0 = (const float*)d_in[12];
    const float* b0  = (const float*)d_in[13];
    const float* W1  = (const float*)d_in[14];
    const float* al1 = (const float*)d_in[15];
    const float* ar1 = (const float*)d_in[16];
    const float* b1  = (const float*)d_in[17];

    // workspace layout (bytes)
    char* ws = (char*)d_ws;
    unsigned short* h0b   = (unsigned short*)(ws);               // N*64  bf16 :  6,400,000
    unsigned short* h1b   = (unsigned short*)(ws + 6400000);     // N*256 bf16 : 25,600,000
    unsigned short* featb = (unsigned short*)(ws + 32000000);    // N*256 bf16 : 25,600,000
    float* el    = (float*)(ws + 57600000);                      //    800,000
    float* er    = (float*)(ws + 58400000);                      //    800,000
    int*   cnt   = (int*)  (ws + 59200000);                      //    200,000
    int*   offs  = (int*)  (ws + 59400000);                      //    200,064 (padded)
    int*   esort = (int*)  (ws + 59600128);                      //  3,200,000
    unsigned short* wpc = (unsigned short*)(ws + 62800128);      //  4*16KB =  65,536
    unsigned short* wpt = (unsigned short*)(ws + 62865664);      // 16*16KB = 262,144
    unsigned short* wpr = (unsigned short*)(ws + 63127808);      // 16*16KB = 262,144
    unsigned short* wp0 = (unsigned short*)(ws + 63389952);      //  2*16KB =  32,768
    unsigned short* wp1 = (unsigned short*)(ws + 63422720);      //  8*16KB = 131,072
    float4* mbuf = (float4*)(ws + 63553792);                     //    800,000
    float4* zbuf = (float4*)(ws + 64353792);                     //    800,000
    if (ws_size < 65153792ull) return;                           // end of layout

    float* outh = (float*)d_out;                       // N*256 final h
    float4* atto = (float4*)(outh + (size_t)NN * 256); // E*4: eesort scratch, then final att

    // weight packing (fragment-order bf16; fusion packs exclude the ones-row)
    pack_w_fusion<<<(4 * 16 * 64 + 255) / 256, 256, 0, stream>>>(Wc, wpc, 129, 4);
    pack_w_fusion<<<(16 * 16 * 64 + 255) / 256, 256, 0, stream>>>(Wt, wpt, 513, 16);
    pack_w_fusion<<<(16 * 16 * 64 + 255) / 256, 256, 0, stream>>>(Wr, wpr, 513, 16);
    pack_w_gemm<<<(2 * 16 * 64 + 255) / 256, 256, 0, stream>>>(W0, wp0, 64, 256);
    pack_w_gemm<<<(8 * 16 * 64 + 255) / 256, 256, 0, stream>>>(W1, wp1, 256, 256);

    // Stage A: trilinear fusion (MFMA, double-buffered)
    fusion_mfma<<<(NN + 63) / 64, 256, 0, stream>>>(hc, ht, hr, wpc, wpt, wpr,
                                                    Wc, Wt, Wr, fw, fb, h0b);

    // CSR by dst
    hipMemsetAsync(cnt, 0, NN * sizeof(int), stream);
    hist_kernel<<<(EE + 255) / 256, 256, 0, stream>>>(dst, cnt);
    scan_kernel<<<1, 1024, 0, stream>>>(cnt, offs);
    hipMemsetAsync(cnt, 0, NN * sizeof(int), stream);
    scatter_kernel<<<(EE + 255) / 256, 256, 0, stream>>>(dst, offs, cnt, esort);

    // GAT layer 0
    gemm_mfma<64><<<(NN + 63) / 64, 256, 0, stream>>>(h0b, wp0, featb);
    elr_kernel<<<(NN * 64 + 255) / 256, 256, 0, stream>>>(featb, al0, ar0, el, er);
    edge_prep<<<(EE + 255) / 256, 256, 0, stream>>>(esort, src, dst, el, er, atto);
    gat_agg<0, 0, 1><<<(NN * 64 + 255) / 256, 256, 0, stream>>>(
        esort, src, offs, featb, atto, nullptr, b0, outh, h1b, nullptr, nullptr);

    // GAT layer 1
    gemm_mfma<256><<<(NN + 63) / 64, 256, 0, stream>>>(h1b, wp1, featb);
    elr_kernel<<<(NN * 64 + 255) / 256, 256, 0, stream>>>(featb, al1, ar1, el, er);
    edge_prep<<<(EE + 255) / 256, 256, 0, stream>>>(esort, src, dst, el, er, atto);
    gat_agg<1, 1, 0><<<(NN * 64 + 255) / 256, 256, 0, stream>>>(
        esort, src, offs, featb, atto, outh, b1, outh, nullptr, mbuf, zbuf);
    att_final<<<(EE + 255) / 256, 256, 0, stream>>>(src, dst, el, er, mbuf, zbuf, atto);
}